// Round 4
// baseline (342.354 us; speedup 1.0000x reference)
//
#include <hip/hip_runtime.h>

// TorchNeighborList, N=4096, cutoff=5, no PBC.
// Output layout (float32, flat, P = N(N-1)/2 = 8,386,560):
//   [0,2P) idx_i | [2P,4P) idx_j | [4P,10P) Rij | [10P,16P) cell_offset
//   [16P,18P) mask | [18P] num_pairs
// Ordering: stable argsort by source idx of concat(triu_i, triu_j) ->
//   per atom a: partners j>a ascending, then i<a ascending. Valid rows dense.

#define NA 4096
static constexpr int PP = 8386560;          // N(N-1)/2
static constexpr int TP = 2 * PP;           // 16,773,120
static constexpr int N4 = 18 * PP / 4;      // 37,739,520 float4s = [0,18P)
static constexpr int PP4 = PP;              // first P float4s = idx regions

typedef float floatx4 __attribute__((ext_vector_type(4)));   // builtin vec type
                                                             // (nontemporal ok)

__device__ __forceinline__ float dist2_exact(float dx, float dy, float dz) {
    return __fadd_rn(__fadd_rn(__fmul_rn(dx, dx), __fmul_rn(dy, dy)),
                     __fmul_rn(dz, dz));
}

// ---- K1: per-atom neighbor count (1 wave per atom) -----------------------
__global__ void count_kernel(const float* __restrict__ pos, int* __restrict__ cnt) {
    int wid = threadIdx.x >> 6, lane = threadIdx.x & 63;
    int a = blockIdx.x * 4 + wid;
    float ax = pos[3 * a + 0], ay = pos[3 * a + 1], az = pos[3 * a + 2];
    int c = 0;
    for (int base = 0; base < NA; base += 64) {
        int p = base + lane;
        float dx = pos[3 * p + 0] - ax;
        float dy = pos[3 * p + 1] - ay;
        float dz = pos[3 * p + 2] - az;
        if (p != a && __fsqrt_rn(dist2_exact(dx, dy, dz)) < 5.0f) c++;
    }
    for (int off = 32; off; off >>= 1) c += __shfl_down(c, off, 64);
    if (lane == 0) cnt[a] = c;
}

// ---- K2: whole-output fill, nontemporal float4 streaming stores ----------
__global__ void fill_kernel(floatx4* __restrict__ out4) {
    const int stride = gridDim.x * blockDim.x;           // 1,048,576
    for (int i = blockIdx.x * blockDim.x + threadIdx.x; i < N4; i += stride) {
        float v = (i < PP4) ? 4096.0f : 0.0f;            // idx regions get sentinel
        floatx4 val = {v, v, v, v};
        __builtin_nontemporal_store(val, &out4[i]);
    }
}

// ---- K3: inline exclusive scan + rank-ordered scatter (1 wave per atom) --
__global__ void scatter_kernel(const float* __restrict__ pos, const int* __restrict__ cnt,
                               float* __restrict__ out) {
    int wid = threadIdx.x >> 6, lane = threadIdx.x & 63;
    int a = blockIdx.x * 4 + wid;
    float ax = pos[3 * a + 0], ay = pos[3 * a + 1], az = pos[3 * a + 2];

    // exclusive prefix over cnt[0..a)  (16 KB, L2-resident)
    int s = 0;
    for (int i = lane; i < a; i += 64) s += cnt[i];
    for (int off = 32; off; off >>= 1) s += __shfl_down(s, off, 64);
    int o = __shfl(s, 0, 64);

    if (a == NA - 1 && lane == 0) out[18 * PP] = (float)(o + cnt[a]);  // num_pairs

    // phase 0: partners > a ascending; phase 1: partners < a ascending
    for (int phase = 0; phase < 2; ++phase) {
        int lo = (phase == 0) ? a + 1 : 0;
        int hi = (phase == 0) ? NA : a;
        for (int base = lo & ~63; base < hi; base += 64) {
            int p = base + lane;
            bool valid = (p >= lo) && (p < hi);
            float px = 0.f, py = 0.f, pz = 0.f;
            if (valid) {
                px = pos[3 * p + 0]; py = pos[3 * p + 1]; pz = pos[3 * p + 2];
                valid = __fsqrt_rn(dist2_exact(px - ax, py - ay, pz - az)) < 5.0f;
            }
            unsigned long long m = __ballot(valid);
            if (valid) {
                int idx = o + __popcll(m & ((1ull << lane) - 1ull));
                out[idx] = (float)a;                      // idx_i
                out[TP + idx] = (float)p;                 // idx_j
                int r = 2 * TP + 3 * idx;                 // Rij row (fits int32)
                out[r + 0] = px - ax;
                out[r + 1] = py - ay;
                out[r + 2] = pz - az;
                out[8 * TP + idx] = 1.0f;                 // mask
            }
            o += __popcll(m);
        }
    }
}

extern "C" void kernel_launch(void* const* d_in, const int* in_sizes, int n_in,
                              void* d_out, int out_size, void* d_ws, size_t ws_size,
                              hipStream_t stream) {
    const float* pos = (const float*)d_in[0];   // [4096,3] f32
    float* out = (float*)d_out;
    int* cnt = (int*)d_ws;

    count_kernel<<<NA / 4, 256, 0, stream>>>(pos, cnt);
    // fill launched TWICE deliberately (idempotent): total-time delta vs R1
    // directly measures the new nontemporal fill's duration (bisection).
    fill_kernel<<<4096, 256, 0, stream>>>((floatx4*)out);
    fill_kernel<<<4096, 256, 0, stream>>>((floatx4*)out);
    scatter_kernel<<<NA / 4, 256, 0, stream>>>(pos, cnt, out);
}

// Round 5
// 166.926 us; speedup vs baseline: 2.0509x; 2.0509x over previous
//
#include <hip/hip_runtime.h>

// TorchNeighborList, N=4096, cutoff=5, no PBC.
// Output layout (float32, flat; P = N(N-1)/2 = 8,386,560; TP = 2P rows):
//   [0,TP) idx_i | [TP,2TP) idx_j | [2TP,5TP) Rij | [5TP,8TP) cell_offset
//   [8TP,9TP) mask | [9TP] num_pairs
// Ordering: stable argsort by source idx of concat(triu_i, triu_j) ->
//   per atom a: partners j>a ascending, then i<a ascending.
// Valid rows are the dense prefix [0, np). Padding: idx=4096, Rij=0, mask=0.
//
// Strategy: count -> scan (offsets + np + region table + boundary scalars)
//   -> ONE fused kernel: 1024 scatter blocks (dispatch first, hidden) +
//      147,420 fill blocks doing ONE float4 store per thread (memset-like
//      sequential stream; R4 bisection showed grid-stride fill = 3.8 TB/s
//      vs memset 6.85 TB/s). Fill covers only padding (disjoint from scatter).

#define NA 4096
static constexpr int PP = 8386560;              // N(N-1)/2
static constexpr int TP = 2 * PP;               // 16,773,120 rows
static constexpr int NFLOATS = 9 * TP;          // 150,958,080 floats (excl. num_pairs)
static constexpr int SCATTER_BLOCKS = NA / 4;   // 1024 (4 waves/block, 1 wave/atom)
static constexpr int FILL_BLOCKS = NFLOATS / 4 / 256;  // 147,420 (1 float4/thread)

typedef float floatx4 __attribute__((ext_vector_type(4)));

__device__ __forceinline__ float dist2_exact(float dx, float dy, float dz) {
    return __fadd_rn(__fadd_rn(__fmul_rn(dx, dx), __fmul_rn(dy, dy)),
                     __fmul_rn(dz, dz));
}

// ---- K1: per-atom neighbor count (1 wave per atom) -----------------------
__global__ void count_kernel(const float* __restrict__ pos, int* __restrict__ cnt) {
    int wid = threadIdx.x >> 6, lane = threadIdx.x & 63;
    int a = blockIdx.x * 4 + wid;
    float ax = pos[3 * a + 0], ay = pos[3 * a + 1], az = pos[3 * a + 2];
    int c = 0;
    for (int base = 0; base < NA; base += 64) {
        int p = base + lane;
        float dx = pos[3 * p + 0] - ax;
        float dy = pos[3 * p + 1] - ay;
        float dz = pos[3 * p + 2] - az;
        if (p != a && __fsqrt_rn(dist2_exact(dx, dy, dz)) < 5.0f) c++;
    }
    for (int off = 32; off; off >>= 1) c += __shfl_down(c, off, 64);
    if (lane == 0) cnt[a] = c;
}

// ---- K2: scan -> per-atom offsets, num_pairs, fill-region table ----------
// Fill regions (floats), all padding, disjoint from scatter's [0,np) ranks:
//   r0 [np, TP)          sentinel 4096   (idx_i padding)
//   r1 [TP+np, 2TP)      sentinel 4096   (idx_j padding)
//   r2 [2TP+3np, 8TP)    zero            (Rij padding + all cell_offset)
//   r3 [8TP+np, 9TP)     zero            (mask padding)
// tbl[0..3] = cumulative float4-store counts e0..e3; tbl[4+r] = base float4
// index of region r's aligned interior. Unaligned heads (<=3 floats/region)
// are written here by thread 0. Region ends are all 16B-aligned.
__global__ void scan_kernel(const int* __restrict__ cnt, int* __restrict__ off,
                            int* __restrict__ tbl, float* __restrict__ out) {
    __shared__ int sdata[1024];
    int tid = threadIdx.x;
    int v[4];
    int s = 0;
    for (int k = 0; k < 4; k++) { v[k] = cnt[tid * 4 + k]; s += v[k]; }
    sdata[tid] = s;
    __syncthreads();
    for (int d = 1; d < 1024; d <<= 1) {
        int t = (tid >= d) ? sdata[tid - d] : 0;
        __syncthreads();
        sdata[tid] += t;
        __syncthreads();
    }
    int excl = tid ? sdata[tid - 1] : 0;
    for (int k = 0; k < 4; k++) { off[tid * 4 + k] = excl; excl += v[k]; }
    if (tid == 0) {
        int np = sdata[1023];
        out[NFLOATS] = (float)np;                       // num_pairs
        int rs[4] = { np, TP + np, 2 * TP + 3 * np, 8 * TP + np };
        int re[4] = { TP, 2 * TP, 8 * TP, 9 * TP };
        int prefix = 0;
        for (int r = 0; r < 4; r++) {
            float val = (r < 2) ? 4096.0f : 0.0f;
            int sF = rs[r], eF = re[r];
            int pre = (4 - (sF & 3)) & 3;
            if (pre > eF - sF) pre = eF - sF;
            for (int k = 0; k < pre; k++) out[sF + k] = val;  // unaligned head
            int as = sF + pre;
            tbl[4 + r] = as >> 2;                       // aligned base (float4)
            prefix += (eF - as) >> 2;
            tbl[r] = prefix;                            // cumulative e_r
        }
    }
}

// ---- K3: fused scatter (blocks 0..1023) + padding fill (rest) ------------
__global__ void fused_kernel(const float* __restrict__ pos, const int* __restrict__ off,
                             const int* __restrict__ tbl, float* __restrict__ out) {
    int bid = blockIdx.x;
    if (bid >= SCATTER_BLOCKS) {
        // --- fill: exactly one float4 store per thread, sequential stream ---
        int t = (bid - SCATTER_BLOCKS) * 256 + threadIdx.x;
        int e0 = tbl[0], e1 = tbl[1], e2 = tbl[2], e3 = tbl[3];
        if (t < e3) {
            int r = (t >= e0) + (t >= e1) + (t >= e2);
            int prev = r ? tbl[r - 1] : 0;
            int a4 = tbl[4 + r] + (t - prev);
            float v = (r < 2) ? 4096.0f : 0.0f;
            floatx4 val = {v, v, v, v};
            ((floatx4*)out)[a4] = val;
        }
        return;
    }
    // --- scatter: 1 wave per atom, rank-ordered compaction ---
    int wid = threadIdx.x >> 6, lane = threadIdx.x & 63;
    int a = bid * 4 + wid;
    float ax = pos[3 * a + 0], ay = pos[3 * a + 1], az = pos[3 * a + 2];
    int o = off[a];
    // phase 0: partners > a ascending; phase 1: partners < a ascending
    for (int phase = 0; phase < 2; ++phase) {
        int lo = (phase == 0) ? a + 1 : 0;
        int hi = (phase == 0) ? NA : a;
        for (int base = lo & ~63; base < hi; base += 64) {
            int p = base + lane;
            bool valid = (p >= lo) && (p < hi);
            float px = 0.f, py = 0.f, pz = 0.f;
            if (valid) {
                px = pos[3 * p + 0]; py = pos[3 * p + 1]; pz = pos[3 * p + 2];
                valid = __fsqrt_rn(dist2_exact(px - ax, py - ay, pz - az)) < 5.0f;
            }
            unsigned long long m = __ballot(valid);
            if (valid) {
                int idx = o + __popcll(m & ((1ull << lane) - 1ull));
                out[idx] = (float)a;                      // idx_i
                out[TP + idx] = (float)p;                 // idx_j
                int r = 2 * TP + 3 * idx;                 // Rij row
                out[r + 0] = px - ax;
                out[r + 1] = py - ay;
                out[r + 2] = pz - az;
                out[8 * TP + idx] = 1.0f;                 // mask
            }
            o += __popcll(m);
        }
    }
}

extern "C" void kernel_launch(void* const* d_in, const int* in_sizes, int n_in,
                              void* d_out, int out_size, void* d_ws, size_t ws_size,
                              hipStream_t stream) {
    const float* pos = (const float*)d_in[0];   // [4096,3] f32
    float* out = (float*)d_out;
    int* cnt = (int*)d_ws;          // [0,4096)
    int* off = cnt + NA;            // [4096,8192)
    int* tbl = off + NA;            // [8192,8200)

    count_kernel<<<NA / 4, 256, 0, stream>>>(pos, cnt);
    scan_kernel<<<1, 1024, 0, stream>>>(cnt, off, tbl, out);
    fused_kernel<<<SCATTER_BLOCKS + FILL_BLOCKS, 256, 0, stream>>>(pos, off, tbl, out);
}

// Round 6
// 155.505 us; speedup vs baseline: 2.2016x; 1.0734x over previous
//
#include <hip/hip_runtime.h>

// TorchNeighborList, N=4096, cutoff=5, no PBC.
// Output layout (float32, flat; P = N(N-1)/2 = 8,386,560; TP = 2P rows):
//   [0,TP) idx_i | [TP,2TP) idx_j | [2TP,5TP) Rij | [5TP,8TP) cell_offset
//   [8TP,9TP) mask | [9TP] num_pairs
// Ordering: stable argsort by source idx of concat(triu_i, triu_j) ->
//   per atom a: partners j>a ascending, then i<a ascending.
// Valid rows are the dense prefix [0, np). Padding: idx=4096, Rij=0, mask=0.
//
// R5 finding: custom fill kernels (grid-stride, nt, one-store-per-thread) all
// plateau at ~3.85 TB/s while rocclr fillBufferAligned hits 6.8 TB/s on the
// same pages. So: delegate ALL padding to memset nodes (static sizes, values
// are single 32-bit/byte patterns), then scatter overwrites the valid prefix.

#define NA 4096
static constexpr int PP = 8386560;             // N(N-1)/2
static constexpr int TP = 2 * PP;              // 16,773,120 rows
static constexpr int NF = 9 * TP;              // 150,958,080 floats (excl. num_pairs)

__device__ __forceinline__ float dist2_exact(float dx, float dy, float dz) {
    return __fadd_rn(__fadd_rn(__fmul_rn(dx, dx), __fmul_rn(dy, dy)),
                     __fmul_rn(dz, dz));
}

// ---- K1: per-atom neighbor count (1 wave per atom) -----------------------
__global__ void count_kernel(const float* __restrict__ pos, int* __restrict__ cnt) {
    int wid = threadIdx.x >> 6, lane = threadIdx.x & 63;
    int a = blockIdx.x * 4 + wid;
    float ax = pos[3 * a + 0], ay = pos[3 * a + 1], az = pos[3 * a + 2];
    int c = 0;
    for (int base = 0; base < NA; base += 64) {
        int p = base + lane;
        float dx = pos[3 * p + 0] - ax;
        float dy = pos[3 * p + 1] - ay;
        float dz = pos[3 * p + 2] - az;
        if (p != a && __fsqrt_rn(dist2_exact(dx, dy, dz)) < 5.0f) c++;
    }
    for (int off = 32; off; off >>= 1) c += __shfl_down(c, off, 64);
    if (lane == 0) cnt[a] = c;
}

// ---- K2: exclusive scan of counts -> per-atom offsets + num_pairs --------
__global__ void scan_kernel(const int* __restrict__ cnt, int* __restrict__ off,
                            float* __restrict__ out) {
    __shared__ int sdata[1024];
    int tid = threadIdx.x;
    int v[4];
    int s = 0;
    for (int k = 0; k < 4; k++) { v[k] = cnt[tid * 4 + k]; s += v[k]; }
    sdata[tid] = s;
    __syncthreads();
    for (int d = 1; d < 1024; d <<= 1) {
        int t = (tid >= d) ? sdata[tid - d] : 0;
        __syncthreads();
        sdata[tid] += t;
        __syncthreads();
    }
    int excl = tid ? sdata[tid - 1] : 0;
    for (int k = 0; k < 4; k++) { off[tid * 4 + k] = excl; excl += v[k]; }
    if (tid == 1023) out[NF] = (float)sdata[1023];     // num_pairs
}

// ---- K3: rank-ordered scatter of valid rows (1 wave per atom) ------------
__global__ void scatter_kernel(const float* __restrict__ pos, const int* __restrict__ off,
                               float* __restrict__ out) {
    int wid = threadIdx.x >> 6, lane = threadIdx.x & 63;
    int a = blockIdx.x * 4 + wid;
    float ax = pos[3 * a + 0], ay = pos[3 * a + 1], az = pos[3 * a + 2];
    int o = off[a];
    // phase 0: partners > a ascending; phase 1: partners < a ascending
    for (int phase = 0; phase < 2; ++phase) {
        int lo = (phase == 0) ? a + 1 : 0;
        int hi = (phase == 0) ? NA : a;
        for (int base = lo & ~63; base < hi; base += 64) {
            int p = base + lane;
            bool valid = (p >= lo) && (p < hi);
            float px = 0.f, py = 0.f, pz = 0.f;
            if (valid) {
                px = pos[3 * p + 0]; py = pos[3 * p + 1]; pz = pos[3 * p + 2];
                valid = __fsqrt_rn(dist2_exact(px - ax, py - ay, pz - az)) < 5.0f;
            }
            unsigned long long m = __ballot(valid);
            if (valid) {
                int idx = o + __popcll(m & ((1ull << lane) - 1ull));
                out[idx] = (float)a;                      // idx_i
                out[TP + idx] = (float)p;                 // idx_j
                int r = 2 * TP + 3 * idx;                 // Rij row
                out[r + 0] = px - ax;
                out[r + 1] = py - ay;
                out[r + 2] = pz - az;
                out[8 * TP + idx] = 1.0f;                 // mask
            }
            o += __popcll(m);
        }
    }
}

extern "C" void kernel_launch(void* const* d_in, const int* in_sizes, int n_in,
                              void* d_out, int out_size, void* d_ws, size_t ws_size,
                              hipStream_t stream) {
    const float* pos = (const float*)d_in[0];   // [4096,3] f32
    float* out = (float*)d_out;
    int* cnt = (int*)d_ws;          // [0,4096)
    int* off = cnt + NA;            // [4096,8192)

    // Padding via rocclr fill kernels (6.8 TB/s proven on these pages):
    // idx_i + idx_j regions <- 4096.0f (bits 0x45800000), 2*TP words = 134 MB
    hipMemsetD32Async((hipDeviceptr_t)out, 0x45800000, (size_t)2 * TP, stream);
    // Rij + cell_offset + mask regions <- 0, 7*TP floats = 470 MB
    hipMemsetAsync(out + (size_t)2 * TP, 0, (size_t)7 * TP * sizeof(float), stream);

    count_kernel<<<NA / 4, 256, 0, stream>>>(pos, cnt);
    scan_kernel<<<1, 1024, 0, stream>>>(cnt, off, out);
    scatter_kernel<<<NA / 4, 256, 0, stream>>>(pos, off, out);
}

// Round 7
// 150.227 us; speedup vs baseline: 2.2789x; 1.0351x over previous
//
#include <hip/hip_runtime.h>

// TorchNeighborList, N=4096, cutoff=5, no PBC.
// Output layout (float32, flat; P = N(N-1)/2 = 8,386,560; TP = 2P rows):
//   [0,TP) idx_i | [TP,2TP) idx_j | [2TP,5TP) Rij | [5TP,8TP) cell_offset
//   [8TP,9TP) mask | [9TP] num_pairs
// Ordering: stable argsort by source idx of concat(triu_i, triu_j) ->
//   per atom a: partners j>a ascending, then i<a ascending.
// Valid rows are the dense prefix [0, np). Padding: idx=4096, Rij=0, mask=0.
//
// Structure (R6 consolidation): padding via rocclr memset nodes (fastest
// observed in-sequence fill, ~4.6 TB/s; custom kernels plateau at 3.85),
// scan fused into scatter (per-wave prefix over 16 KB cnt array).
// 4 graph nodes total: count -> memsetD32 -> memset0 -> scatter.

#define NA 4096
static constexpr int PP = 8386560;             // N(N-1)/2
static constexpr int TP = 2 * PP;              // 16,773,120 rows
static constexpr int NF = 9 * TP;              // 150,958,080 floats (excl. num_pairs)

__device__ __forceinline__ float dist2_exact(float dx, float dy, float dz) {
    return __fadd_rn(__fadd_rn(__fmul_rn(dx, dx), __fmul_rn(dy, dy)),
                     __fmul_rn(dz, dz));
}

// ---- K1: per-atom neighbor count (1 wave per atom) -----------------------
__global__ void count_kernel(const float* __restrict__ pos, int* __restrict__ cnt) {
    int wid = threadIdx.x >> 6, lane = threadIdx.x & 63;
    int a = blockIdx.x * 4 + wid;
    float ax = pos[3 * a + 0], ay = pos[3 * a + 1], az = pos[3 * a + 2];
    int c = 0;
    for (int base = 0; base < NA; base += 64) {
        int p = base + lane;
        float dx = pos[3 * p + 0] - ax;
        float dy = pos[3 * p + 1] - ay;
        float dz = pos[3 * p + 2] - az;
        if (p != a && __fsqrt_rn(dist2_exact(dx, dy, dz)) < 5.0f) c++;
    }
    for (int off = 32; off; off >>= 1) c += __shfl_down(c, off, 64);
    if (lane == 0) cnt[a] = c;
}

// ---- K2: inline exclusive scan + rank-ordered scatter (1 wave per atom) --
__global__ void scatter_kernel(const float* __restrict__ pos, const int* __restrict__ cnt,
                               float* __restrict__ out) {
    int wid = threadIdx.x >> 6, lane = threadIdx.x & 63;
    int a = blockIdx.x * 4 + wid;
    float ax = pos[3 * a + 0], ay = pos[3 * a + 1], az = pos[3 * a + 2];

    // exclusive prefix over cnt[0..a)  (cnt = 16 KB, L2-resident)
    int s = 0;
    for (int i = lane; i < a; i += 64) s += cnt[i];
    for (int off = 32; off; off >>= 1) s += __shfl_down(s, off, 64);
    int o = __shfl(s, 0, 64);

    if (a == NA - 1 && lane == 0) out[NF] = (float)(o + cnt[a]);   // num_pairs

    // phase 0: partners > a ascending; phase 1: partners < a ascending
    for (int phase = 0; phase < 2; ++phase) {
        int lo = (phase == 0) ? a + 1 : 0;
        int hi = (phase == 0) ? NA : a;
        for (int base = lo & ~63; base < hi; base += 64) {
            int p = base + lane;
            bool valid = (p >= lo) && (p < hi);
            float px = 0.f, py = 0.f, pz = 0.f;
            if (valid) {
                px = pos[3 * p + 0]; py = pos[3 * p + 1]; pz = pos[3 * p + 2];
                valid = __fsqrt_rn(dist2_exact(px - ax, py - ay, pz - az)) < 5.0f;
            }
            unsigned long long m = __ballot(valid);
            if (valid) {
                int idx = o + __popcll(m & ((1ull << lane) - 1ull));
                out[idx] = (float)a;                      // idx_i
                out[TP + idx] = (float)p;                 // idx_j
                int r = 2 * TP + 3 * idx;                 // Rij row
                out[r + 0] = px - ax;
                out[r + 1] = py - ay;
                out[r + 2] = pz - az;
                out[8 * TP + idx] = 1.0f;                 // mask
            }
            o += __popcll(m);
        }
    }
}

extern "C" void kernel_launch(void* const* d_in, const int* in_sizes, int n_in,
                              void* d_out, int out_size, void* d_ws, size_t ws_size,
                              hipStream_t stream) {
    const float* pos = (const float*)d_in[0];   // [4096,3] f32
    float* out = (float*)d_out;
    int* cnt = (int*)d_ws;          // [0,4096)

    count_kernel<<<NA / 4, 256, 0, stream>>>(pos, cnt);
    // idx_i + idx_j regions <- 4096.0f (bits 0x45800000), 2*TP words = 134 MB
    hipMemsetD32Async((hipDeviceptr_t)out, 0x45800000, (size_t)2 * TP, stream);
    // Rij + cell_offset + mask regions <- 0, 7*TP floats = 470 MB
    hipMemsetAsync(out + (size_t)2 * TP, 0, (size_t)7 * TP * sizeof(float), stream);
    scatter_kernel<<<NA / 4, 256, 0, stream>>>(pos, cnt, out);
}